// Round 5
// baseline (787.283 us; speedup 1.0000x reference)
//
#include <hip/hip_runtime.h>
#include <hip/hip_bf16.h>

// RGCN segment MM:  out[d] = sum_r ( sum_{e: dst=d, et=r} feat[src[e]] ) @ W[r]
// Bucket = (dst>>7)*R + et (6256 buckets) built by one bump-allocator scatter
// (rec = src | dl<<sbits). Fused kernel, per (block of 128 dst, r), per
// 128-edge chunk (PROJECT-THEN-AGGREGATE, all-vectorized LDS):
//   stage: edge-parallel 16B gathers -> G[128e][136] (edge-major) + dlv[]
//   MFMA1: T = G @ W[r]   (A = G rows b128; B = wtb n-major b128, L1/L2-hot)
//   pack:  T C-frags -> bf16 Tt[n][e]  (each lane holds 4 consecutive e for
//          fixed n -> natural b64 writes; the transpose is free via C-layout)
//   MFMA2: out^T += Tt @ P^T  (A = Tt rows b128; B = one-hot P^T built in
//          registers from dlv compares, STANDARD k-indexing)
// acc holds out^T across all r; epilogue = 16 float4 stores per thread.
// Equivalent math (linearity); only new rounding = bf16 round of per-chunk T.
//
// R4/R5 lesson (FAILED): tr16-based operand swap mis-mapped fragments ->
// abandoned. All fragment patterns here are isomorphic to the final GEMM of
// the PASSING R3 kernel (A rows b128 / B n-major b128 / C col=lm,row=lq*4+i).
// R3 lesson: 128 scalar 4-way-conflicted ds_read_u16/chunk was ~90us -> gone.

#define FEAT 128
#define LDG 136          // G row stride (bf16 elems)
#define LDT 136          // Tt row stride (bf16 elems)
#define CAP 512          // records per bucket (lambda~256, 16 sigma headroom)
#define CHUNK 128

typedef __attribute__((ext_vector_type(8))) short short8;
typedef __attribute__((ext_vector_type(8))) __bf16 bf16x8;
typedef __attribute__((ext_vector_type(4))) float f32x4;
typedef __attribute__((ext_vector_type(2))) unsigned int uint2v;

__device__ __forceinline__ unsigned f2bf(float x) {
    union { float f; unsigned u; } v; v.f = x;
    unsigned r = v.u + 0x7FFFu + ((v.u >> 16) & 1u);   // RNE
    return r >> 16;
}

// ---------------- conversions ----------------
__global__ void cvt_feat_kernel(const float* __restrict__ f,
                                ushort* __restrict__ o, int n8) {
    int i = blockIdx.x * blockDim.x + threadIdx.x;
    if (i >= n8) return;
    const float4* f4 = (const float4*)f;
    float4 a = f4[2 * i], b = f4[2 * i + 1];
    union { ushort u[8]; int4 v; } pk;
    pk.u[0] = f2bf(a.x); pk.u[1] = f2bf(a.y); pk.u[2] = f2bf(a.z); pk.u[3] = f2bf(a.w);
    pk.u[4] = f2bf(b.x); pk.u[5] = f2bf(b.y); pk.u[6] = f2bf(b.z); pk.u[7] = f2bf(b.w);
    ((int4*)o)[i] = pk.v;
}

// W[r][k][n] fp32 -> Wt[n][r*128+k] bf16 (K-stacked, n-major)
__global__ void cvt_w_kernel(const float* __restrict__ w,
                             ushort* __restrict__ wt, int total, int KW) {
    int i = blockIdx.x * blockDim.x + threadIdx.x;
    if (i >= total) return;
    int n = i / KW;
    int rk = i - n * KW;
    int r = rk >> 7, k = rk & 127;
    wt[i] = (ushort)f2bf(w[(r << 14) + (k << 7) + n]);
}

// ---------------- bucketize edges (bump allocator) ----------------
__global__ void scatter_kernel(const int* __restrict__ dst,
                               const int* __restrict__ et,
                               const int* __restrict__ src, int E, int R,
                               int sbits, int* __restrict__ cursor,
                               int* __restrict__ recs) {
    int i = blockIdx.x * blockDim.x + threadIdx.x;
    int stride = gridDim.x * blockDim.x;
    for (; i < E; i += stride) {
        int d = dst[i];
        int b = (d >> 7) * R + et[i];
        int p = atomicAdd(&cursor[b], 1);
        if (p < CAP) recs[(size_t)b * CAP + p] = src[i] | ((d & 127) << sbits);
    }
}

// ---------------- fused project + aggregate ----------------
__global__ __launch_bounds__(256, 2)
void fused_kernel(const ushort* __restrict__ featb,
                  const ushort* __restrict__ wtb,
                  const int* __restrict__ recs,
                  const int* __restrict__ cursor,
                  float* __restrict__ out, int N, int R, int KW, int sbits) {
    __shared__ __align__(16) ushort G[CHUNK * LDG];    // 34816 B edge-major
    __shared__ __align__(16) ushort Tt[FEAT * LDT];    // 34816 B n-major
    __shared__ __align__(16) ushort dlv[CHUNK];        // dst-low per edge slot

    int t = threadIdx.x;
    int qid = t >> 4, c = t & 15;          // edge slot / col chunk for gather
    int lane = t & 63, wid = t >> 6;
    int lm = lane & 15, lq = lane >> 4;    // MFMA fragment coords
    int blk = blockIdx.x, base = blk * 128;
    int er = (wid >> 1) * 64;              // MFMA1 edge-row / pack e quadrant
    int nw = (wid & 1) * 64;               // MFMA1 n-col / pack n quadrant
    int fr = (wid >> 1) * 64;              // MFMA2 n-row quadrant (out^T rows)
    int dc = (wid & 1) * 64;               // MFMA2 dst-col quadrant
    int smask = (1 << sbits) - 1;

    f32x4 acc[16];                         // out^T, accumulated across all r
    #pragma unroll
    for (int i = 0; i < 16; i++) acc[i] = (f32x4){0.f, 0.f, 0.f, 0.f};

    for (int r = 0; r < R; r++) {
        int bkt = blk * R + r;
        int ecnt = cursor[bkt];
        if (ecnt <= 0) continue;           // block-uniform
        if (ecnt > CAP) ecnt = CAP;
        const int* rb = recs + (size_t)bkt * CAP;

        // prologue: records + gathers for chunk 0
        int rcv[8]; uint4 gvv[8];
        #pragma unroll
        for (int p = 0; p < 8; p++) {
            int j = p * 16 + qid;
            rcv[p] = (j < ecnt) ? rb[j] : -1;
        }
        #pragma unroll
        for (int p = 0; p < 8; p++) {
            if (rcv[p] >= 0)
                gvv[p] = *(const uint4*)(featb +
                         (size_t)(rcv[p] & smask) * FEAT + c * 8);
            else
                gvv[p] = (uint4){0u, 0u, 0u, 0u};   // zero pad rows
        }

        for (int c0 = 0; c0 < ecnt; c0 += CHUNK) {
            // next chunk's records (issue early)
            int rcvn[8];
            #pragma unroll
            for (int p = 0; p < 8; p++) {
                int j = c0 + CHUNK + p * 16 + qid;
                rcvn[p] = (j < ecnt) ? rb[j] : -1;
            }
            // ---- stage current chunk -> G (edge-major) + dlv ----
            #pragma unroll
            for (int p = 0; p < 8; p++)
                *(uint4*)&G[(p * 16 + qid) * LDG + c * 8] = gvv[p];
            if (c == 0) {
                #pragma unroll
                for (int p = 0; p < 8; p++)
                    dlv[p * 16 + qid] = (rcv[p] >= 0)
                        ? (ushort)((rcv[p] >> sbits) & 127) : (ushort)0xFFFF;
            }
            __syncthreads();                               // bar1

            // next chunk's feature gathers -- hide under both MFMA phases
            uint4 gvvn[8];
            #pragma unroll
            for (int p = 0; p < 8; p++) {
                if (rcvn[p] >= 0)
                    gvvn[p] = *(const uint4*)(featb +
                              (size_t)(rcvn[p] & smask) * FEAT + c * 8);
                else
                    gvvn[p] = (uint4){0u, 0u, 0u, 0u};
            }

            // ---- MFMA1: T = G @ W[r] (64x64 quadrant per wave) ----
            f32x4 Ta[16];
            #pragma unroll
            for (int i = 0; i < 16; i++) Ta[i] = (f32x4){0.f, 0.f, 0.f, 0.f};
            const ushort* bpw = wtb + (size_t)(nw + lm) * KW + r * FEAT;
            #pragma unroll
            for (int ks = 0; ks < 4; ks++) {
                int kof = ks * 32 + lq * 8;
                short8 af[4], bw[4];
                #pragma unroll
                for (int tm = 0; tm < 4; tm++)
                    af[tm] = *(const short8*)&G[(er + tm * 16 + lm) * LDG + kof];
                #pragma unroll
                for (int tn = 0; tn < 4; tn++)
                    bw[tn] = *(const short8*)(bpw + (size_t)(tn * 16) * KW + kof);
                #pragma unroll
                for (int tm = 0; tm < 4; tm++)
                    #pragma unroll
                    for (int tn = 0; tn < 4; tn++)
                        Ta[tm * 4 + tn] = __builtin_amdgcn_mfma_f32_16x16x32_bf16(
                            __builtin_bit_cast(bf16x8, af[tm]),
                            __builtin_bit_cast(bf16x8, bw[tn]),
                            Ta[tm * 4 + tn], 0, 0, 0);
            }

            // ---- pack T -> Tt[n][e] (transpose free via C-frag layout) ----
            // C-frag (tm,tn) elem i: edge = er+tm*16+lq*4+i, n = nw+tn*16+lm
            #pragma unroll
            for (int tm = 0; tm < 4; tm++)
                #pragma unroll
                for (int tn = 0; tn < 4; tn++) {
                    f32x4 v = Ta[tm * 4 + tn];
                    union { unsigned u[2]; uint2v w; } pk;
                    pk.u[0] = f2bf(v[0]) | (f2bf(v[1]) << 16);
                    pk.u[1] = f2bf(v[2]) | (f2bf(v[3]) << 16);
                    *(uint2v*)&Tt[(nw + tn * 16 + lm) * LDT +
                                  er + tm * 16 + lq * 4] = pk.w;
                }
            __syncthreads();                               // bar2

            // ---- MFMA2: acc(out^T) += Tt @ P^T ----
            #pragma unroll
            for (int ks = 0; ks < 4; ks++) {
                int kof = ks * 32 + lq * 8;
                union { ushort u[8]; uint4 v; } dl8;
                dl8.v = *(const uint4*)&dlv[kof];          // broadcast read
                short8 at[4];
                #pragma unroll
                for (int tm = 0; tm < 4; tm++)
                    at[tm] = *(const short8*)&Tt[(fr + tm * 16 + lm) * LDT + kof];
                short8 pb[4];
                #pragma unroll
                for (int tn = 0; tn < 4; tn++) {
                    ushort col = (ushort)(dc + tn * 16 + lm);
                    union { ushort u[8]; short8 s; } b;
                    #pragma unroll
                    for (int q = 0; q < 8; q++)
                        b.u[q] = (dl8.u[q] == col) ? (ushort)0x3F80 : (ushort)0;
                    pb[tn] = b.s;
                }
                #pragma unroll
                for (int tm = 0; tm < 4; tm++)
                    #pragma unroll
                    for (int tn = 0; tn < 4; tn++)
                        acc[tm * 4 + tn] = __builtin_amdgcn_mfma_f32_16x16x32_bf16(
                            __builtin_bit_cast(bf16x8, at[tm]),
                            __builtin_bit_cast(bf16x8, pb[tn]),
                            acc[tm * 4 + tn], 0, 0, 0);
            }
            __syncthreads();                               // bar3 (dlv/G reuse)

            #pragma unroll
            for (int p = 0; p < 8; p++) { rcv[p] = rcvn[p]; gvv[p] = gvvn[p]; }
        }
    }

    // ---- epilogue: out^T frags -> float4 stores ----
    // acc (tm,tn) elem i: n = fr+tm*16+lq*4+i, dst = dc+tn*16+lm
    #pragma unroll
    for (int tn = 0; tn < 4; tn++) {
        int drow = base + dc + tn * 16 + lm;
        if (drow < N) {
            #pragma unroll
            for (int tm = 0; tm < 4; tm++) {
                f32x4 v = acc[tm * 4 + tn];
                *(f32x4*)(out + (size_t)drow * FEAT + fr + tm * 16 + lq * 4) = v;
            }
        }
    }
}

static inline size_t al256(size_t x) { return (x + 255) & ~(size_t)255; }

extern "C" void kernel_launch(void* const* d_in, const int* in_sizes, int n_in,
                              void* d_out, int out_size, void* d_ws,
                              size_t ws_size, hipStream_t stream) {
    const float* feat = (const float*)d_in[0];
    const float* weight = (const float*)d_in[1];
    const int* src = (const int*)d_in[2];
    const int* dst = (const int*)d_in[3];
    const int* et = (const int*)d_in[4];

    int nfeat = in_sizes[0];
    int N = nfeat / FEAT;                    // 100000
    int R = in_sizes[1] / (FEAT * FEAT);     // 8
    int E = in_sizes[2];                     // 1.6M
    int Npad = ((N + 127) / 128) * 128;
    int nblk = Npad / 128;                   // 782
    int NB = nblk * R;                       // 6256 buckets
    int KW = R * FEAT;                       // 1024
    float* out = (float*)d_out;

    int sbits = 1;
    while ((1 << sbits) < N) sbits++;        // 17 for N=100000

    // ---- workspace layout (~28 MB) ----
    char* ws = (char*)d_ws;
    size_t o = 0;
    size_t cur_o  = o; o += al256((size_t)NB * 4);
    size_t recs_o = o; o += al256((size_t)NB * CAP * 4);
    size_t wtb_o  = o; o += al256((size_t)R * FEAT * FEAT * 2);
    size_t featb_o = o;

    int* cursor = (int*)(ws + cur_o);
    int* recs   = (int*)(ws + recs_o);
    ushort* wtb   = (ushort*)(ws + wtb_o);
    ushort* featb = (ushort*)(ws + featb_o);

    hipMemsetAsync(cursor, 0, (size_t)NB * 4, stream);

    int wtotal = R * FEAT * FEAT;
    cvt_w_kernel<<<(wtotal + 255) / 256, 256, 0, stream>>>(weight, wtb, wtotal, KW);
    int n8 = nfeat / 8;
    cvt_feat_kernel<<<(n8 + 255) / 256, 256, 0, stream>>>(feat, featb, n8);

    scatter_kernel<<<512, 256, 0, stream>>>(dst, et, src, E, R, sbits,
                                            cursor, recs);

    fused_kernel<<<nblk, 256, 0, stream>>>(featb, wtb, recs, cursor,
                                           out, N, R, KW, sbits);
}

// Round 6
// 485.977 us; speedup vs baseline: 1.6200x; 1.6200x over previous
//
#include <hip/hip_runtime.h>
#include <hip/hip_bf16.h>

// RGCN segment MM:  out[d] = sum_r ( sum_{e: dst=d, et=r} feat[src[e]] ) @ W[r]
// Bucket = (dst>>7)*R + et (6256 buckets) built by one bump-allocator scatter
// (rec = src | dl<<sbits). Fused kernel, per (block of 128 dst, r), per
// 128-edge chunk (PROJECT-THEN-AGGREGATE, verified R6 dataflow):
//   stage: global_load_lds DMA gathers (per-lane global src, linear LDS dest,
//          SOURCE-swizzled: lane loads slice sl^(e&7) so G row-reads are
//          conflict-free with zero VGPR staging cost)   [T21/m104 pattern]
//   MFMA1: T = G @ W[r], in 2 half-passes (Ta[8] not Ta[16] -> no spills)
//   pack:  T C-frags -> bf16 Tt[n][e] (transpose free via C-layout)
//   MFMA2: out^T += Tt @ P^T (one-hot P from dlv compares, registers)
// acc holds out^T across r; epilogue = float4 stores.
//
// R6 lesson: Ta(64)+acc(64)+gvv/gvvn(64)+frags ~260 regs -> ~800MB scratch
// spill traffic (WRITE 649MB vs 51MB out). R7: DMA staging + halved Ta ->
// peak ~160 regs. Barrier C is raw lgkmcnt-only so prefetched stage loads
// stay in flight; barrier A (__syncthreads) drains vmcnt before G is read.

#define FEAT 128
#define LDT 136          // Tt row stride (bf16 elems)
#define CAP 512          // records per bucket (lambda~256, 16 sigma headroom)
#define CHUNK 128

typedef __attribute__((ext_vector_type(8))) short short8;
typedef __attribute__((ext_vector_type(8))) __bf16 bf16x8;
typedef __attribute__((ext_vector_type(4))) float f32x4;
typedef __attribute__((ext_vector_type(2))) unsigned int uint2v;

__device__ __forceinline__ unsigned f2bf(float x) {
    union { float f; unsigned u; } v; v.f = x;
    unsigned r = v.u + 0x7FFFu + ((v.u >> 16) & 1u);   // RNE
    return r >> 16;
}

__device__ __forceinline__ void stage16(const ushort* gsrc, ushort* ldst) {
    __builtin_amdgcn_global_load_lds(
        (const __attribute__((address_space(1))) void*)gsrc,
        (__attribute__((address_space(3))) void*)ldst, 16, 0, 0);
}

// ---------------- conversions ----------------
__global__ void cvt_feat_kernel(const float* __restrict__ f,
                                ushort* __restrict__ o, int n8) {
    int i = blockIdx.x * blockDim.x + threadIdx.x;
    if (i >= n8) return;
    const float4* f4 = (const float4*)f;
    float4 a = f4[2 * i], b = f4[2 * i + 1];
    union { ushort u[8]; int4 v; } pk;
    pk.u[0] = f2bf(a.x); pk.u[1] = f2bf(a.y); pk.u[2] = f2bf(a.z); pk.u[3] = f2bf(a.w);
    pk.u[4] = f2bf(b.x); pk.u[5] = f2bf(b.y); pk.u[6] = f2bf(b.z); pk.u[7] = f2bf(b.w);
    ((int4*)o)[i] = pk.v;
}

// W[r][k][n] fp32 -> Wt[n][r*128+k] bf16 (K-stacked, n-major)
__global__ void cvt_w_kernel(const float* __restrict__ w,
                             ushort* __restrict__ wt, int total, int KW) {
    int i = blockIdx.x * blockDim.x + threadIdx.x;
    if (i >= total) return;
    int n = i / KW;
    int rk = i - n * KW;
    int r = rk >> 7, k = rk & 127;
    wt[i] = (ushort)f2bf(w[(r << 14) + (k << 7) + n]);
}

// ---------------- bucketize edges (bump allocator) ----------------
__global__ void scatter_kernel(const int* __restrict__ dst,
                               const int* __restrict__ et,
                               const int* __restrict__ src, int E, int R,
                               int sbits, int* __restrict__ cursor,
                               int* __restrict__ recs) {
    int i = blockIdx.x * blockDim.x + threadIdx.x;
    int stride = gridDim.x * blockDim.x;
    for (; i < E; i += stride) {
        int d = dst[i];
        int b = (d >> 7) * R + et[i];
        int p = atomicAdd(&cursor[b], 1);
        if (p < CAP) recs[(size_t)b * CAP + p] = src[i] | ((d & 127) << sbits);
    }
}

// ---------------- fused project + aggregate ----------------
__global__ __launch_bounds__(256, 2)
void fused_kernel(const ushort* __restrict__ featb,
                  const ushort* __restrict__ wtb,
                  const int* __restrict__ recs,
                  const int* __restrict__ cursor,
                  const ushort* __restrict__ zrow,
                  float* __restrict__ out, int N, int R, int KW, int sbits) {
    __shared__ __align__(16) ushort G[CHUNK * FEAT];   // 32768 B, src-swizzled
    __shared__ __align__(16) ushort Tt[FEAT * LDT];    // 34816 B n-major
    __shared__ __align__(16) ushort dlv[CHUNK];        // dst-low per edge slot

    int t = threadIdx.x;
    int lane = t & 63, wid = t >> 6;
    int lm = lane & 15, lq = lane >> 4;    // MFMA fragment coords
    int sl = lane & 15;                    // staging slice position 0..15
    int e_of = lane >> 4;                  // staging edge offset 0..3
    int blk = blockIdx.x, base = blk * 128;
    int er = (wid >> 1) * 64;              // MFMA1 edge-row / pack e quadrant
    int nw = (wid & 1) * 64;               // MFMA1 n-col / pack n quadrant
    int fr = (wid >> 1) * 64;              // MFMA2 n-row quadrant (out^T rows)
    int dc = (wid & 1) * 64;               // MFMA2 dst-col quadrant
    int smask = (1 << sbits) - 1;

    f32x4 acc[16];                         // out^T, accumulated across all r
    #pragma unroll
    for (int i = 0; i < 16; i++) acc[i] = (f32x4){0.f, 0.f, 0.f, 0.f};

    for (int r = 0; r < R; r++) {
        int bkt = blk * R + r;
        int ecnt = cursor[bkt];
        if (ecnt <= 0) continue;           // block-uniform
        if (ecnt > CAP) ecnt = CAP;
        const int* rb = recs + (size_t)bkt * CAP;

        // ---- prologue: issue DMA stage for chunk 0 + dl regs ----
        int dlp[8];
        #pragma unroll
        for (int p = 0; p < 8; p++) {
            int e = wid * 32 + p * 4 + e_of;           // chunk slot 0..127
            int j = e;
            int rc = (j < ecnt) ? rb[j] : -1;
            dlp[p] = (rc >= 0) ? ((rc >> sbits) & 127) : 0xFFFF;
            const ushort* gs = (rc >= 0)
                ? featb + (size_t)(rc & smask) * FEAT + ((sl ^ (e & 7)) * 8)
                : zrow + sl * 8;
            stage16(gs, &G[(wid * 32 + p * 4) * FEAT]);  // uniform base, lane*16
        }

        for (int c0 = 0; c0 < ecnt; c0 += CHUNK) {
            // ---- dlv from regs (stage loads still in flight) ----
            if (sl == 0) {
                #pragma unroll
                for (int p = 0; p < 8; p++)
                    dlv[wid * 32 + p * 4 + e_of] = (ushort)dlp[p];
            }
            __syncthreads();               // A: drains vmcnt -> G ready; dlv ready

            // ---- MFMA1: T = G @ W[r], two half-passes (regs!) + pack ----
            const ushort* bpw = wtb + (size_t)(nw + lm) * KW + r * FEAT;
            #pragma unroll
            for (int h = 0; h < 2; h++) {
                f32x4 Ta[8];
                #pragma unroll
                for (int i = 0; i < 8; i++) Ta[i] = (f32x4){0.f, 0.f, 0.f, 0.f};
                #pragma unroll
                for (int ks = 0; ks < 4; ks++) {
                    int kb = ks * 4 + lq;
                    short8 af[2], bw[4];
                    #pragma unroll
                    for (int tm2 = 0; tm2 < 2; tm2++) {
                        int row = er + (2 * h + tm2) * 16 + lm;
                        af[tm2] = *(const short8*)&G[row * FEAT +
                                                     ((kb ^ (row & 7)) << 3)];
                    }
                    #pragma unroll
                    for (int tn = 0; tn < 4; tn++)
                        bw[tn] = *(const short8*)(bpw + (size_t)(tn * 16) * KW +
                                                  ks * 32 + lq * 8);
                    #pragma unroll
                    for (int tm2 = 0; tm2 < 2; tm2++)
                        #pragma unroll
                        for (int tn = 0; tn < 4; tn++)
                            Ta[tm2 * 4 + tn] = __builtin_amdgcn_mfma_f32_16x16x32_bf16(
                                __builtin_bit_cast(bf16x8, af[tm2]),
                                __builtin_bit_cast(bf16x8, bw[tn]),
                                Ta[tm2 * 4 + tn], 0, 0, 0);
                }
                // pack half: edge = er+tm*16+lq*4+i, n = nw+tn*16+lm
                #pragma unroll
                for (int tm2 = 0; tm2 < 2; tm2++)
                    #pragma unroll
                    for (int tn = 0; tn < 4; tn++) {
                        int tm = 2 * h + tm2;
                        f32x4 v = Ta[tm2 * 4 + tn];
                        union { unsigned u[2]; uint2v w; } pk;
                        pk.u[0] = f2bf(v[0]) | (f2bf(v[1]) << 16);
                        pk.u[1] = f2bf(v[2]) | (f2bf(v[3]) << 16);
                        *(uint2v*)&Tt[(nw + tn * 16 + lm) * LDT +
                                      er + tm * 16 + lq * 4] = pk.w;
                    }
            }
            __syncthreads();               // B: Tt ready; G readers done

            // ---- prefetch: issue next chunk's DMA stage (hides under MFMA2) ----
            if (c0 + CHUNK < ecnt) {
                #pragma unroll
                for (int p = 0; p < 8; p++) {
                    int e = wid * 32 + p * 4 + e_of;
                    int j = c0 + CHUNK + e;
                    int rc = (j < ecnt) ? rb[j] : -1;
                    dlp[p] = (rc >= 0) ? ((rc >> sbits) & 127) : 0xFFFF;
                    const ushort* gs = (rc >= 0)
                        ? featb + (size_t)(rc & smask) * FEAT + ((sl ^ (e & 7)) * 8)
                        : zrow + sl * 8;
                    stage16(gs, &G[(wid * 32 + p * 4) * FEAT]);
                }
            }

            // ---- MFMA2: acc(out^T) += Tt @ P^T ----
            #pragma unroll
            for (int ks = 0; ks < 4; ks++) {
                int kof = ks * 32 + lq * 8;
                union { ushort u[8]; uint4 v; } dl8;
                dl8.v = *(const uint4*)&dlv[kof];
                short8 at[4];
                #pragma unroll
                for (int tm = 0; tm < 4; tm++)
                    at[tm] = *(const short8*)&Tt[(fr + tm * 16 + lm) * LDT + kof];
                short8 pb[4];
                #pragma unroll
                for (int tn = 0; tn < 4; tn++) {
                    ushort col = (ushort)(dc + tn * 16 + lm);
                    union { ushort u[8]; short8 s; } b;
                    #pragma unroll
                    for (int q = 0; q < 8; q++)
                        b.u[q] = (dl8.u[q] == col) ? (ushort)0x3F80 : (ushort)0;
                    pb[tn] = b.s;
                }
                #pragma unroll
                for (int tm = 0; tm < 4; tm++)
                    #pragma unroll
                    for (int tn = 0; tn < 4; tn++)
                        acc[tm * 4 + tn] = __builtin_amdgcn_mfma_f32_16x16x32_bf16(
                            __builtin_bit_cast(bf16x8, at[tm]),
                            __builtin_bit_cast(bf16x8, pb[tn]),
                            acc[tm * 4 + tn], 0, 0, 0);
            }

            // C: raw barrier, LDS-drain only -- keep stage DMA in flight
            asm volatile("s_waitcnt lgkmcnt(0)" ::: "memory");
            __builtin_amdgcn_s_barrier();
        }
    }

    // ---- epilogue: out^T frags -> float4 stores ----
    // acc (tm,tn) elem i: n = fr+tm*16+lq*4+i, dst = dc+tn*16+lm
    #pragma unroll
    for (int tn = 0; tn < 4; tn++) {
        int drow = base + dc + tn * 16 + lm;
        if (drow < N) {
            #pragma unroll
            for (int tm = 0; tm < 4; tm++) {
                f32x4 v = acc[tm * 4 + tn];
                *(f32x4*)(out + (size_t)drow * FEAT + fr + tm * 16 + lq * 4) = v;
            }
        }
    }
}

static inline size_t al256(size_t x) { return (x + 255) & ~(size_t)255; }

extern "C" void kernel_launch(void* const* d_in, const int* in_sizes, int n_in,
                              void* d_out, int out_size, void* d_ws,
                              size_t ws_size, hipStream_t stream) {
    const float* feat = (const float*)d_in[0];
    const float* weight = (const float*)d_in[1];
    const int* src = (const int*)d_in[2];
    const int* dst = (const int*)d_in[3];
    const int* et = (const int*)d_in[4];

    int nfeat = in_sizes[0];
    int N = nfeat / FEAT;                    // 100000
    int R = in_sizes[1] / (FEAT * FEAT);     // 8
    int E = in_sizes[2];                     // 1.6M
    int Npad = ((N + 127) / 128) * 128;
    int nblk = Npad / 128;                   // 782
    int NB = nblk * R;                       // 6256 buckets
    int KW = R * FEAT;                       // 1024
    float* out = (float*)d_out;

    int sbits = 1;
    while ((1 << sbits) < N) sbits++;        // 17 for N=100000

    // ---- workspace layout (~28 MB) ----
    char* ws = (char*)d_ws;
    size_t o = 0;
    size_t cur_o  = o; o += al256((size_t)NB * 4);
    size_t zrow_o = o; o += 256;                       // 256 B zero page
    size_t recs_o = o; o += al256((size_t)NB * CAP * 4);
    size_t wtb_o  = o; o += al256((size_t)R * FEAT * FEAT * 2);
    size_t featb_o = o;

    int* cursor = (int*)(ws + cur_o);
    ushort* zrow = (ushort*)(ws + zrow_o);
    int* recs   = (int*)(ws + recs_o);
    ushort* wtb   = (ushort*)(ws + wtb_o);
    ushort* featb = (ushort*)(ws + featb_o);

    hipMemsetAsync(cursor, 0, (size_t)NB * 4 + 256, stream);  // cursor + zrow

    int wtotal = R * FEAT * FEAT;
    cvt_w_kernel<<<(wtotal + 255) / 256, 256, 0, stream>>>(weight, wtb, wtotal, KW);
    int n8 = nfeat / 8;
    cvt_feat_kernel<<<(n8 + 255) / 256, 256, 0, stream>>>(feat, featb, n8);

    scatter_kernel<<<512, 256, 0, stream>>>(dst, et, src, E, R, sbits,
                                            cursor, recs);

    fused_kernel<<<nblk, 256, 0, stream>>>(featb, wtb, recs, cursor, zrow,
                                           out, N, R, KW, sbits);
}

// Round 7
// 458.205 us; speedup vs baseline: 1.7182x; 1.0606x over previous
//
#include <hip/hip_runtime.h>
#include <hip/hip_bf16.h>

// RGCN segment MM:  out[d] = sum_r ( sum_{e: dst=d, et=r} feat[src[e]] ) @ W[r]
// Bucket = (dst>>7)*R + et (6256 buckets) built by one bump-allocator scatter
// (rec = src | dl<<sbits). Fused kernel, per (block of 128 dst, r), per
// 128-edge chunk (PROJECT-THEN-AGGREGATE, verified R6/R7 dataflow):
//   stage: register gathers (normal VMEM) -> ds_write into XOR-swizzled G
//   MFMA1: Ta = G @ Wl   (A = G rows b128 swz; B = Wl n-major b128 swz,
//          Wl = W[r] slice staged to LDS ONCE per r from r-major wt)
//   pack:  Ta C-frags -> bf16 Tt[n][e] (XOR-swizzled, ALIASED onto G --
//          pack runs after barrier B when G is dead)
//   MFMA2: acc(out^T) += Tt @ P^T (one-hot P from dlv compares, registers)
// Epilogue: float4 stores of out^T frags.
//
// R7 lesson: global_load_lds with random per-lane addrs serializes (hbm_gbps
// 930->740, fused 313us); per-chunk global wtb reads scatter 64 lines/instr.
// R8: reg-gather staging (both swizzle sides controlled), W in LDS per r,
// G/Tt aliased via full-Ta ordering, single gvv buffer (~190 live regs, no
// spill -- R6's 260-reg failure was gvv+gvvn+Ta+acc all live).

#define FEAT 128
#define CAP 512          // records per bucket (lambda~256, 16 sigma headroom)
#define CHUNK 128

typedef __attribute__((ext_vector_type(8))) short short8;
typedef __attribute__((ext_vector_type(8))) __bf16 bf16x8;
typedef __attribute__((ext_vector_type(4))) float f32x4;
typedef __attribute__((ext_vector_type(2))) unsigned int uint2v;

__device__ __forceinline__ unsigned f2bf(float x) {
    union { float f; unsigned u; } v; v.f = x;
    unsigned r = v.u + 0x7FFFu + ((v.u >> 16) & 1u);   // RNE
    return r >> 16;
}

// ---------------- conversions ----------------
__global__ void cvt_feat_kernel(const float* __restrict__ f,
                                ushort* __restrict__ o, int n8) {
    int i = blockIdx.x * blockDim.x + threadIdx.x;
    if (i >= n8) return;
    const float4* f4 = (const float4*)f;
    float4 a = f4[2 * i], b = f4[2 * i + 1];
    union { ushort u[8]; int4 v; } pk;
    pk.u[0] = f2bf(a.x); pk.u[1] = f2bf(a.y); pk.u[2] = f2bf(a.z); pk.u[3] = f2bf(a.w);
    pk.u[4] = f2bf(b.x); pk.u[5] = f2bf(b.y); pk.u[6] = f2bf(b.z); pk.u[7] = f2bf(b.w);
    ((int4*)o)[i] = pk.v;
}

// W[r][k][n] fp32 -> wt[r][n][k] bf16 (r-major 32KB slices for LDS staging)
__global__ void cvt_w_kernel(const float* __restrict__ w,
                             ushort* __restrict__ wt, int total) {
    int i = blockIdx.x * blockDim.x + threadIdx.x;
    if (i >= total) return;
    int r = i >> 14, n = (i >> 7) & 127, k = i & 127;
    wt[i] = (ushort)f2bf(w[(r << 14) + (k << 7) + n]);
}

// ---------------- bucketize edges (bump allocator) ----------------
__global__ void scatter_kernel(const int* __restrict__ dst,
                               const int* __restrict__ et,
                               const int* __restrict__ src, int E, int R,
                               int sbits, int* __restrict__ cursor,
                               int* __restrict__ recs) {
    int i = blockIdx.x * blockDim.x + threadIdx.x;
    int stride = gridDim.x * blockDim.x;
    for (; i < E; i += stride) {
        int d = dst[i];
        int b = (d >> 7) * R + et[i];
        int p = atomicAdd(&cursor[b], 1);
        if (p < CAP) recs[(size_t)b * CAP + p] = src[i] | ((d & 127) << sbits);
    }
}

// ---------------- fused project + aggregate ----------------
__global__ __launch_bounds__(256, 2)
void fused_kernel(const ushort* __restrict__ featb,
                  const ushort* __restrict__ wtr,
                  const int* __restrict__ recs,
                  const int* __restrict__ cursor,
                  float* __restrict__ out, int N, int R, int sbits) {
    __shared__ __align__(16) ushort GS[128 * 128];  // G (chunk) / Tt, aliased
    __shared__ __align__(16) ushort Wl[128 * 128];  // W[r] n-major, swizzled
    __shared__ __align__(16) ushort dlv[CHUNK];     // dst-low per edge slot

    int t = threadIdx.x;
    int qid = t >> 4, cc = t & 15;         // staging row-slot / col-block
    int lane = t & 63, wid = t >> 6;
    int lm = lane & 15, lq = lane >> 4;    // MFMA fragment coords
    int blk = blockIdx.x, base = blk * 128;
    int er = (wid >> 1) * 64;              // MFMA1 edge-row / pack e quadrant
    int nw = (wid & 1) * 64;               // MFMA1 n-col / pack n quadrant
    int fr = er, dc = nw;                  // MFMA2 n-row / dst-col quadrants
    int smask = (1 << sbits) - 1;
    int l7 = lm & 7;

    f32x4 acc[16];                         // out^T, accumulated across all r
    #pragma unroll
    for (int i = 0; i < 16; i++) acc[i] = (f32x4){0.f, 0.f, 0.f, 0.f};

    for (int r = 0; r < R; r++) {
        int bkt = blk * R + r;
        int ecnt = cursor[bkt];
        if (ecnt <= 0) continue;           // block-uniform
        if (ecnt > CAP) ecnt = CAP;
        const int* rb = recs + (size_t)bkt * CAP;

        // ---- stage W[r] slice -> Wl (XOR-swizzled), once per r ----
        // (previous r's Wl readers finished before last barrier C)
        const ushort* wsrc = wtr + ((size_t)r << 14);
        #pragma unroll
        for (int j = 0; j < 8; j++) {
            int idx = j * 2048 + t * 8;                // n = j*16+qid, blk cc
            uint4 v = *(const uint4*)(wsrc + idx);
            int n = idx >> 7;
            *(uint4*)&Wl[(n << 7) + ((cc ^ (qid & 7)) << 3)] = v;
        }

        // ---- prologue: records + gathers for chunk 0 ----
        int dlp[8]; uint4 gvv[8];
        #pragma unroll
        for (int p = 0; p < 8; p++) {
            int j = p * 16 + qid;
            int rc = (j < ecnt) ? rb[j] : -1;
            dlp[p] = (rc >= 0) ? ((rc >> sbits) & 127) : 0xFFFF;
            if (rc >= 0)
                gvv[p] = *(const uint4*)(featb + (size_t)(rc & smask) * FEAT + cc * 8);
            else
                gvv[p] = (uint4){0u, 0u, 0u, 0u};
        }

        for (int c0 = 0; c0 < ecnt; c0 += CHUNK) {
            // ---- top: write G (swizzled) + dlv ----
            #pragma unroll
            for (int p = 0; p < 8; p++) {
                int row = p * 16 + qid;
                *(uint4*)&GS[(row << 7) + ((cc ^ (qid & 7)) << 3)] = gvv[p];
            }
            if (cc == 0) {
                #pragma unroll
                for (int p = 0; p < 8; p++)
                    dlv[p * 16 + qid] = (ushort)dlp[p];
            }
            __syncthreads();                           // A (no vmem in flight)

            // ---- MFMA1: Ta = G @ Wl, full 16 frags ----
            f32x4 Ta[16];
            #pragma unroll
            for (int i = 0; i < 16; i++) Ta[i] = (f32x4){0.f, 0.f, 0.f, 0.f};
            #pragma unroll
            for (int ks = 0; ks < 4; ks++) {
                int kb = ks * 4 + lq;
                int kswz = (kb ^ l7) << 3;
                short8 af[4], bw[4];
                #pragma unroll
                for (int tm = 0; tm < 4; tm++)
                    af[tm] = *(const short8*)&GS[((er + tm * 16 + lm) << 7) + kswz];
                #pragma unroll
                for (int tn = 0; tn < 4; tn++)
                    bw[tn] = *(const short8*)&Wl[((nw + tn * 16 + lm) << 7) + kswz];
                #pragma unroll
                for (int tm = 0; tm < 4; tm++)
                    #pragma unroll
                    for (int tn = 0; tn < 4; tn++)
                        Ta[tm * 4 + tn] = __builtin_amdgcn_mfma_f32_16x16x32_bf16(
                            __builtin_bit_cast(bf16x8, af[tm]),
                            __builtin_bit_cast(bf16x8, bw[tn]),
                            Ta[tm * 4 + tn], 0, 0, 0);
            }
            __syncthreads();                           // B (G dead -> Tt may alias)

            // record prefetch for next chunk (rb latency hides under pack)
            int rcn[8];
            bool more = (c0 + CHUNK < ecnt);
            if (more) {
                #pragma unroll
                for (int p = 0; p < 8; p++) {
                    int j = c0 + CHUNK + p * 16 + qid;
                    rcn[p] = (j < ecnt) ? rb[j] : -1;
                }
            }

            // ---- pack Ta -> Tt[n][e] (swizzled, aliased on GS) ----
            // C-frag (tm,tn) elem i: edge = er+tm*16+lq*4+i, n = nw+tn*16+lm
            #pragma unroll
            for (int tm = 0; tm < 4; tm++)
                #pragma unroll
                for (int tn = 0; tn < 4; tn++) {
                    f32x4 v = Ta[tm * 4 + tn];
                    union { unsigned u[2]; uint2v w; } pk;
                    pk.u[0] = f2bf(v[0]) | (f2bf(v[1]) << 16);
                    pk.u[1] = f2bf(v[2]) | (f2bf(v[3]) << 16);
                    int w = nw + tn * 16 + lm;
                    int eb = er + tm * 16 + lq * 4;
                    *(uint2v*)&GS[(w << 7) + (((eb >> 3) ^ (w & 7)) << 3) +
                                  (eb & 7)] = pk.w;
                }

            // gather prefetch (hides under B2 + MFMA2)
            if (more) {
                #pragma unroll
                for (int p = 0; p < 8; p++) {
                    int rc = rcn[p];
                    dlp[p] = (rc >= 0) ? ((rc >> sbits) & 127) : 0xFFFF;
                    if (rc >= 0)
                        gvv[p] = *(const uint4*)(featb +
                                 (size_t)(rc & smask) * FEAT + cc * 8);
                    else
                        gvv[p] = (uint4){0u, 0u, 0u, 0u};
                }
            }

            // B2: raw barrier (keep prefetch gathers in flight)
            asm volatile("s_waitcnt lgkmcnt(0)" ::: "memory");
            __builtin_amdgcn_s_barrier();
            __builtin_amdgcn_sched_barrier(0);

            // ---- MFMA2: acc(out^T) += Tt @ P^T ----
            #pragma unroll
            for (int ks = 0; ks < 4; ks++) {
                int kof = ks * 32 + lq * 8;
                int kb2 = ks * 4 + lq;
                union { ushort u[8]; uint4 v; } dl8;
                dl8.v = *(const uint4*)&dlv[kof];
                short8 at[4];
                #pragma unroll
                for (int tm = 0; tm < 4; tm++) {
                    int row = fr + tm * 16 + lm;
                    at[tm] = *(const short8*)&GS[(row << 7) + ((kb2 ^ l7) << 3)];
                }
                short8 pb[4];
                #pragma unroll
                for (int tn = 0; tn < 4; tn++) {
                    ushort col = (ushort)(dc + tn * 16 + lm);
                    union { ushort u[8]; short8 s; } b;
                    #pragma unroll
                    for (int q = 0; q < 8; q++)
                        b.u[q] = (dl8.u[q] == col) ? (ushort)0x3F80 : (ushort)0;
                    pb[tn] = b.s;
                }
                #pragma unroll
                for (int tm = 0; tm < 4; tm++)
                    #pragma unroll
                    for (int tn = 0; tn < 4; tn++)
                        acc[tm * 4 + tn] = __builtin_amdgcn_mfma_f32_16x16x32_bf16(
                            __builtin_bit_cast(bf16x8, at[tm]),
                            __builtin_bit_cast(bf16x8, pb[tn]),
                            acc[tm * 4 + tn], 0, 0, 0);
            }

            // C: raw barrier (MFMA2 reads done; prefetch stays in flight)
            asm volatile("s_waitcnt lgkmcnt(0)" ::: "memory");
            __builtin_amdgcn_s_barrier();
            __builtin_amdgcn_sched_barrier(0);
        }
    }

    // ---- epilogue: out^T frags -> float4 stores ----
    // acc (tm,tn) elem i: n = fr+tm*16+lq*4+i, dst = dc+tn*16+lm
    #pragma unroll
    for (int tn = 0; tn < 4; tn++) {
        int drow = base + dc + tn * 16 + lm;
        if (drow < N) {
            #pragma unroll
            for (int tm = 0; tm < 4; tm++) {
                f32x4 v = acc[tm * 4 + tn];
                *(f32x4*)(out + (size_t)drow * FEAT + fr + tm * 16 + lq * 4) = v;
            }
        }
    }
}

static inline size_t al256(size_t x) { return (x + 255) & ~(size_t)255; }

extern "C" void kernel_launch(void* const* d_in, const int* in_sizes, int n_in,
                              void* d_out, int out_size, void* d_ws,
                              size_t ws_size, hipStream_t stream) {
    const float* feat = (const float*)d_in[0];
    const float* weight = (const float*)d_in[1];
    const int* src = (const int*)d_in[2];
    const int* dst = (const int*)d_in[3];
    const int* et = (const int*)d_in[4];

    int nfeat = in_sizes[0];
    int N = nfeat / FEAT;                    // 100000
    int R = in_sizes[1] / (FEAT * FEAT);     // 8
    int E = in_sizes[2];                     // 1.6M
    int Npad = ((N + 127) / 128) * 128;
    int nblk = Npad / 128;                   // 782
    int NB = nblk * R;                       // 6256 buckets
    float* out = (float*)d_out;

    int sbits = 1;
    while ((1 << sbits) < N) sbits++;        // 17 for N=100000

    // ---- workspace layout (~28 MB) ----
    char* ws = (char*)d_ws;
    size_t o = 0;
    size_t cur_o  = o; o += al256((size_t)NB * 4);
    size_t recs_o = o; o += al256((size_t)NB * CAP * 4);
    size_t wtr_o  = o; o += al256((size_t)R * FEAT * FEAT * 2);
    size_t featb_o = o;

    int* cursor = (int*)(ws + cur_o);
    int* recs   = (int*)(ws + recs_o);
    ushort* wtr   = (ushort*)(ws + wtr_o);
    ushort* featb = (ushort*)(ws + featb_o);

    hipMemsetAsync(cursor, 0, (size_t)NB * 4, stream);

    int wtotal = R * FEAT * FEAT;
    cvt_w_kernel<<<(wtotal + 255) / 256, 256, 0, stream>>>(weight, wtr, wtotal);
    int n8 = nfeat / 8;
    cvt_feat_kernel<<<(n8 + 255) / 256, 256, 0, stream>>>(feat, featb, n8);

    scatter_kernel<<<512, 256, 0, stream>>>(dst, et, src, E, R, sbits,
                                            cursor, recs);

    fused_kernel<<<nblk, 256, 0, stream>>>(featb, wtr, recs, cursor,
                                           out, N, R, sbits);
}